// Round 3
// baseline (397.652 us; speedup 1.0000x reference)
//
#include <hip/hip_runtime.h>
#include <math.h>

using bf_t = unsigned short;
typedef short s16x4 __attribute__((ext_vector_type(4)));
typedef short s16x8 __attribute__((ext_vector_type(8)));
typedef float f32x4 __attribute__((ext_vector_type(4)));

__device__ __forceinline__ bf_t f2bf(float f) {
  unsigned u = __float_as_uint(f);
  u += 0x7FFFu + ((u >> 16) & 1u);
  return (bf_t)(u >> 16);
}
__device__ __forceinline__ float bf2f(bf_t h) {
  return __uint_as_float(((unsigned)h) << 16);
}

union V8 { s16x8 v; s16x4 h[2]; };
__device__ __forceinline__ s16x8 ld_frag(const bf_t* p) {
  V8 u;
  u.h[0] = *(const s16x4*)p;
  u.h[1] = *(const s16x4*)(p + 16);
  return u.v;
}

#define MFMA(A, B, C) __builtin_amdgcn_mfma_f32_16x16x32_bf16((A), (B), (C), 0, 0, 0)

// ---------------------------------------------------------------------------
// fp32 -> bf16 conversion (4 elems / thread)
// ---------------------------------------------------------------------------
__global__ void cvt_kernel(const float* __restrict__ in, bf_t* __restrict__ out, int n4) {
  int i = blockIdx.x * blockDim.x + threadIdx.x;
  if (i >= n4) return;
  float4 v = ((const float4*)in)[i];
  ushort4 o;
  o.x = f2bf(v.x); o.y = f2bf(v.y); o.z = f2bf(v.z); o.w = f2bf(v.w);
  ((ushort4*)out)[i] = o;
}

// ---------------------------------------------------------------------------
// bf16 GEMM: C[M][N] = A[M][K] * Bw[N][K]^T  (both operands K-contiguous)
// 128x128 tile, 4 waves (2x2), each wave 64x64 = 4x4 frags of 16x16x32 MFMA.
// EPI=0: scatter QKV (N=3072 concat) with V transposed.  EPI=1: fp32 out.
// ---------------------------------------------------------------------------
template <int EPI>
__global__ __launch_bounds__(256) void gemm_kernel(
    const bf_t* __restrict__ A, const bf_t* __restrict__ Bw,
    float* __restrict__ Cf,
    bf_t* __restrict__ Qb, bf_t* __restrict__ Kb, bf_t* __restrict__ Vt,
    int M, int N, int K) {
  constexpr int BKP = 40;  // 32 + pad -> 80B row stride, 16B aligned, 2-way bank alias (free)
  __shared__ bf_t As[128 * BKP];
  __shared__ bf_t Bs[128 * BKP];
  const int t = threadIdx.x;
  const int lane = t & 63;
  const int w = t >> 6;
  const int wr = w >> 1, wc = w & 1;
  const int col = lane & 15;
  const int kg = lane >> 4;
  const int m0 = blockIdx.y * 128;
  const int n0 = blockIdx.x * 128;

  f32x4 acc[4][4] = {};

  for (int k0 = 0; k0 < K; k0 += 32) {
    // stage 128x32 of A and B (2 passes, 8 bf16 / thread / pass)
#pragma unroll
    for (int p = 0; p < 2; ++p) {
      int idx = t + p * 256;
      int row = idx >> 2;
      int kk = (idx & 3) << 3;
      *(s16x8*)&As[row * BKP + kk] = *(const s16x8*)&A[(size_t)(m0 + row) * K + k0 + kk];
      *(s16x8*)&Bs[row * BKP + kk] = *(const s16x8*)&Bw[(size_t)(n0 + row) * K + k0 + kk];
    }
    __syncthreads();
    s16x8 af[4], bfg[4];
#pragma unroll
    for (int mi = 0; mi < 4; ++mi)
      af[mi] = ld_frag(&As[(wr * 64 + mi * 16 + col) * BKP + kg * 4]);
#pragma unroll
    for (int ni = 0; ni < 4; ++ni)
      bfg[ni] = ld_frag(&Bs[(wc * 64 + ni * 16 + col) * BKP + kg * 4]);
#pragma unroll
    for (int mi = 0; mi < 4; ++mi)
#pragma unroll
      for (int ni = 0; ni < 4; ++ni)
        acc[mi][ni] = MFMA(af[mi], bfg[ni], acc[mi][ni]);
    __syncthreads();
  }

#pragma unroll
  for (int mi = 0; mi < 4; ++mi)
#pragma unroll
    for (int ni = 0; ni < 4; ++ni)
#pragma unroll
      for (int r = 0; r < 4; ++r) {
        int gm = m0 + wr * 64 + mi * 16 + kg * 4 + r;
        int gn = n0 + wc * 64 + ni * 16 + col;
        float v = acc[mi][ni][r];
        if constexpr (EPI == 0) {
          int which = gn >> 10;
          int wn = gn & 1023;
          int h = wn >> 6, d = wn & 63;
          int b = gm >> 11, s = gm & 2047;
          size_t hb = (size_t)(b * 16 + h);
          if (which == 0)
            Qb[(hb * 2048 + s) * 64 + d] = f2bf(v);
          else if (which == 1)
            Kb[(hb * 2048 + s) * 64 + d] = f2bf(v);
          else
            Vt[(hb * 64 + d) * 2048 + s] = f2bf(v);
        } else {
          Cf[(size_t)gm * N + gn] = v;
        }
      }
}

// ---------------------------------------------------------------------------
// RoPE on Q and K in-place: one thread per (b,h,s,pair); same angle for Q & K.
// sincosf (accurate, full range reduction) -- pos up to 2047 -> angle up to
// ~2047 rad; the native v_sin path's revolution range is not guaranteed there.
// ---------------------------------------------------------------------------
__global__ void rope_kernel(bf_t* __restrict__ Qb, bf_t* __restrict__ Kb,
                            const int* __restrict__ pos, int total) {
  int i = blockIdx.x * blockDim.x + threadIdx.x;
  if (i >= total) return;
  int ip = i & 31;
  int s = (i >> 5) & 2047;
  int bh = i >> 16;  // b*16 + h
  int b = bh >> 4;
  float p = (float)pos[b * 2048 + s];
  // inv_freq = 10000^(-ip/32) = exp2(-ip * log2(10000)/32)
  float ang = p * exp2f(-(float)ip * 0.41524101186f);
  float sv, cv;
  sincosf(ang, &sv, &cv);
  size_t base = ((size_t)bh * 2048 + s) * 64 + ip * 2;
  {
    unsigned u = *(const unsigned*)&Qb[base];
    float x1 = bf2f((bf_t)(u & 0xFFFF)), x2 = bf2f((bf_t)(u >> 16));
    unsigned o = (unsigned)f2bf(x1 * cv - x2 * sv) | ((unsigned)f2bf(x1 * sv + x2 * cv) << 16);
    *(unsigned*)&Qb[base] = o;
  }
  {
    unsigned u = *(const unsigned*)&Kb[base];
    float x1 = bf2f((bf_t)(u & 0xFFFF)), x2 = bf2f((bf_t)(u >> 16));
    unsigned o = (unsigned)f2bf(x1 * cv - x2 * sv) | ((unsigned)f2bf(x1 * sv + x2 * cv) << 16);
    *(unsigned*)&Kb[base] = o;
  }
}

// ---------------------------------------------------------------------------
// Causal flash attention. 1 wave / block; wave owns 64 q-rows x dk=64.
// K-tiles of 32 keys; online softmax (stats per (mi,r) row, reduced across the
// 16-lane col group); P -> bf16 via padded LDS transpose -> PV MFMA.
// ---------------------------------------------------------------------------
__global__ __launch_bounds__(64) void attn_kernel(const bf_t* __restrict__ Qb,
                                                  const bf_t* __restrict__ Kb,
                                                  const bf_t* __restrict__ Vt,
                                                  bf_t* __restrict__ AO) {
  const int lane = threadIdx.x & 63;
  const int col = lane & 15;
  const int kg = lane >> 4;
  const int bh = blockIdx.y;
  const int q0 = blockIdx.x * 64;
  const bf_t* Qp = Qb + (size_t)bh * 2048 * 64;
  const bf_t* Kp = Kb + (size_t)bh * 2048 * 64;
  const bf_t* Vp = Vt + (size_t)bh * 64 * 2048;

  __shared__ bf_t Pl[64 * 40];

  s16x8 qf[4][2];
#pragma unroll
  for (int mi = 0; mi < 4; ++mi)
#pragma unroll
    for (int ks = 0; ks < 2; ++ks)
      qf[mi][ks] = ld_frag(Qp + (size_t)(q0 + mi * 16 + col) * 64 + ks * 32 + kg * 4);

  f32x4 o[4][4] = {};
  float mrun[4][4], lrun[4][4];
#pragma unroll
  for (int mi = 0; mi < 4; ++mi)
#pragma unroll
    for (int r = 0; r < 4; ++r) {
      mrun[mi][r] = -INFINITY;
      lrun[mi][r] = 0.0f;
    }

  for (int kb = 0; kb < q0 + 64; kb += 32) {
    s16x8 kf[2][2];
#pragma unroll
    for (int nk = 0; nk < 2; ++nk)
#pragma unroll
      for (int ks = 0; ks < 2; ++ks)
        kf[nk][ks] = ld_frag(Kp + (size_t)(kb + nk * 16 + col) * 64 + ks * 32 + kg * 4);

    f32x4 sc[4][2] = {};
#pragma unroll
    for (int mi = 0; mi < 4; ++mi)
#pragma unroll
      for (int nk = 0; nk < 2; ++nk)
#pragma unroll
        for (int ks = 0; ks < 2; ++ks)
          sc[mi][nk] = MFMA(qf[mi][ks], kf[nk][ks], sc[mi][nk]);

    const int k0g = kb + col, k1g = kb + 16 + col;
#pragma unroll
    for (int mi = 0; mi < 4; ++mi)
#pragma unroll
      for (int r = 0; r < 4; ++r) {
        int qg = q0 + mi * 16 + kg * 4 + r;
        float s0 = (k0g <= qg) ? sc[mi][0][r] * 0.125f : -INFINITY;
        float s1 = (k1g <= qg) ? sc[mi][1][r] * 0.125f : -INFINITY;
        float mx = fmaxf(s0, s1);
        mx = fmaxf(mx, __shfl_xor(mx, 1));
        mx = fmaxf(mx, __shfl_xor(mx, 2));
        mx = fmaxf(mx, __shfl_xor(mx, 4));
        mx = fmaxf(mx, __shfl_xor(mx, 8));
        float mold = mrun[mi][r];
        float mn = fmaxf(mold, mx);
        float a = __expf(mold - mn);
        float e0 = __expf(s0 - mn);
        float e1 = __expf(s1 - mn);
        sc[mi][0][r] = e0;
        sc[mi][1][r] = e1;
        float rs = e0 + e1;
        rs += __shfl_xor(rs, 1);
        rs += __shfl_xor(rs, 2);
        rs += __shfl_xor(rs, 4);
        rs += __shfl_xor(rs, 8);
        lrun[mi][r] = lrun[mi][r] * a + rs;
        mrun[mi][r] = mn;
#pragma unroll
        for (int ni = 0; ni < 4; ++ni) o[mi][ni][r] *= a;
      }

    __syncthreads();  // protect previous iteration's Pl reads
#pragma unroll
    for (int mi = 0; mi < 4; ++mi)
#pragma unroll
      for (int nk = 0; nk < 2; ++nk)
#pragma unroll
        for (int r = 0; r < 4; ++r)
          Pl[(mi * 16 + kg * 4 + r) * 40 + nk * 16 + col] = f2bf(sc[mi][nk][r]);
    __syncthreads();

    s16x8 pa[4], vf[4];
#pragma unroll
    for (int mi = 0; mi < 4; ++mi) pa[mi] = ld_frag(&Pl[(mi * 16 + col) * 40 + kg * 4]);
#pragma unroll
    for (int ni = 0; ni < 4; ++ni)
      vf[ni] = ld_frag(Vp + (size_t)(ni * 16 + col) * 2048 + kb + kg * 4);
#pragma unroll
    for (int mi = 0; mi < 4; ++mi)
#pragma unroll
      for (int ni = 0; ni < 4; ++ni) o[mi][ni] = MFMA(pa[mi], vf[ni], o[mi][ni]);
  }

  const int b = bh >> 4, h = bh & 15;
#pragma unroll
  for (int mi = 0; mi < 4; ++mi)
#pragma unroll
    for (int r = 0; r < 4; ++r) {
      float inv = 1.0f / lrun[mi][r];
      int qg = q0 + mi * 16 + kg * 4 + r;
#pragma unroll
      for (int ni = 0; ni < 4; ++ni)
        AO[((size_t)b * 2048 + qg) * 1024 + h * 64 + ni * 16 + col] =
            f2bf(o[mi][ni][r] * inv);
    }
}

// ---------------------------------------------------------------------------
extern "C" void kernel_launch(void* const* d_in, const int* in_sizes, int n_in,
                              void* d_out, int out_size, void* d_ws, size_t ws_size,
                              hipStream_t stream) {
  const float* x = (const float*)d_in[0];
  const int* pos = (const int*)d_in[1];
  const float* Wq = (const float*)d_in[2];
  const float* Wk = (const float*)d_in[3];
  const float* Wv = (const float*)d_in[4];
  const float* Wo = (const float*)d_in[5];
  float* out = (float*)d_out;

  char* ws = (char*)d_ws;
  bf_t* xb    = (bf_t*)(ws);                 //  8,388,608 B  [4096][1024]
  bf_t* Wqkvb = (bf_t*)(ws + 8388608);       //  6,291,456 B  [3072][1024]
  bf_t* Wob   = (bf_t*)(ws + 14680064);      //  2,097,152 B  [1024][1024]
  bf_t* Qb    = (bf_t*)(ws + 16777216);      //  8,388,608 B  [2][16][2048][64]
  bf_t* Kb    = (bf_t*)(ws + 25165824);      //  8,388,608 B  [2][16][2048][64]
  bf_t* Vt    = (bf_t*)(ws + 33554432);      //  8,388,608 B  [2][16][64][2048]
  bf_t* AO    = (bf_t*)(ws + 41943040);      //  8,388,608 B  [4096][1024]

  cvt_kernel<<<4096, 256, 0, stream>>>(x, xb, 1048576);
  cvt_kernel<<<1024, 256, 0, stream>>>(Wq, Wqkvb, 262144);
  cvt_kernel<<<1024, 256, 0, stream>>>(Wk, Wqkvb + 1048576, 262144);
  cvt_kernel<<<1024, 256, 0, stream>>>(Wv, Wqkvb + 2097152, 262144);
  cvt_kernel<<<1024, 256, 0, stream>>>(Wo, Wob, 262144);

  gemm_kernel<0><<<dim3(24, 32), 256, 0, stream>>>(xb, Wqkvb, nullptr, Qb, Kb, Vt,
                                                   4096, 3072, 1024);
  rope_kernel<<<8192, 256, 0, stream>>>(Qb, Kb, pos, 2097152);
  attn_kernel<<<dim3(32, 32), 64, 0, stream>>>(Qb, Kb, Vt, AO);
  gemm_kernel<1><<<dim3(8, 32), 256, 0, stream>>>(AO, Wob, out, nullptr, nullptr, nullptr,
                                                  4096, 1024, 1024);
}